// Round 1
// baseline (488.630 us; speedup 1.0000x reference)
//
#include <hip/hip_runtime.h>
#include <hip/hip_bf16.h>

typedef __bf16 bf16x8 __attribute__((ext_vector_type(8)));
typedef float f32x4 __attribute__((ext_vector_type(4)));

static constexpr int T_SEQ  = 384;
static constexpr int NNEUR  = 128;
static constexpr int DMODEL = 512;
static constexpr int NH     = 8;
static constexpr int DH     = 64;
static constexpr int NROWS  = NNEUR * T_SEQ;   // 49152

__device__ __forceinline__ float bf2f(unsigned short u) {
  union { unsigned int i; float f; } x; x.i = ((unsigned int)u) << 16; return x.f;
}
__device__ __forceinline__ unsigned short f2bf(float f) {
  union { float f; unsigned int i; } x; x.f = f;
  unsigned int i = x.i;
  i += 0x7FFFu + ((i >> 16) & 1u);   // RNE
  return (unsigned short)(i >> 16);
}

// ------------------------------------------------------------------
// weights fp32 -> bf16
// ------------------------------------------------------------------
__global__ __launch_bounds__(256) void cvt_w_kernel(
    const float* __restrict__ w0, const float* __restrict__ w1,
    const float* __restrict__ w2, const float* __restrict__ w3,
    unsigned short* __restrict__ o0, unsigned short* __restrict__ o1,
    unsigned short* __restrict__ o2, unsigned short* __restrict__ o3)
{
  const float* w; unsigned short* o;
  switch (blockIdx.y) {
    case 0:  w = w0; o = o0; break;
    case 1:  w = w1; o = o1; break;
    case 2:  w = w2; o = o2; break;
    default: w = w3; o = o3; break;
  }
  int i = (blockIdx.x * 256 + threadIdx.x) * 4;
  float4 v = *reinterpret_cast<const float4*>(w + i);
  union { unsigned short u[4]; uint2 v2; } p;
  p.u[0] = f2bf(v.x); p.u[1] = f2bf(v.y); p.u[2] = f2bf(v.z); p.u[3] = f2bf(v.w);
  *reinterpret_cast<uint2*>(o + i) = p.v2;
}

// ------------------------------------------------------------------
// RMSNorm: x[t][n][d] fp32 -> xt_bf[n][t][d] bf16 (also the residual)
// one wave per row
// ------------------------------------------------------------------
__global__ __launch_bounds__(256) void rmsnorm_kernel(
    const float* __restrict__ x, const float* __restrict__ nw,
    unsigned short* __restrict__ xt)
{
  int wave = threadIdx.x >> 6, lane = threadIdx.x & 63;
  int rid = blockIdx.x * 4 + wave;       // rid = t*128 + n
  int t = rid >> 7, n = rid & 127;
  const float* row = x + (size_t)rid * DMODEL;
  float4 v0 = *reinterpret_cast<const float4*>(row + lane * 8);
  float4 v1 = *reinterpret_cast<const float4*>(row + lane * 8 + 4);
  float ss = v0.x*v0.x + v0.y*v0.y + v0.z*v0.z + v0.w*v0.w
           + v1.x*v1.x + v1.y*v1.y + v1.z*v1.z + v1.w*v1.w;
  #pragma unroll
  for (int off = 32; off; off >>= 1) ss += __shfl_xor(ss, off);
  float sc = rsqrtf(ss * (1.0f / DMODEL) + 1e-6f);
  float4 w0 = *reinterpret_cast<const float4*>(nw + lane * 8);
  float4 w1 = *reinterpret_cast<const float4*>(nw + lane * 8 + 4);
  union { unsigned short u[8]; uint4 v; } p;
  p.u[0] = f2bf(v0.x * sc * w0.x); p.u[1] = f2bf(v0.y * sc * w0.y);
  p.u[2] = f2bf(v0.z * sc * w0.z); p.u[3] = f2bf(v0.w * sc * w0.w);
  p.u[4] = f2bf(v1.x * sc * w1.x); p.u[5] = f2bf(v1.y * sc * w1.y);
  p.u[6] = f2bf(v1.z * sc * w1.z); p.u[7] = f2bf(v1.w * sc * w1.w);
  *reinterpret_cast<uint4*>(xt + ((size_t)n * T_SEQ + t) * DMODEL + lane * 8) = p.v;
}

// ------------------------------------------------------------------
// NT GEMM: C[M x 512] = A[M x 512] * B[512 x 512]^T, all bf16 inputs,
// fp32 accumulate. 128x128 tile, 4 waves (2x2), 16x16x32 MFMA.
// ------------------------------------------------------------------
__device__ __forceinline__ void cstore(float* p, float v) { *p = v; }
__device__ __forceinline__ void cstore(unsigned short* p, float v) { *p = f2bf(v); }

template <typename OutT>
__global__ __launch_bounds__(256, 2) void gemm_nt(
    const unsigned short* __restrict__ A,
    const unsigned short* __restrict__ B,
    OutT* __restrict__ C)
{
  __shared__ alignas(16) unsigned short As[128][72];
  __shared__ alignas(16) unsigned short Bs[128][72];
  const int tid  = threadIdx.x;
  const int wave = tid >> 6, lane = tid & 63;
  const int l15  = lane & 15, quad = lane >> 4;
  const int wm = (wave >> 1) * 64, wn = (wave & 1) * 64;
  const size_t m0 = (size_t)blockIdx.x * 128;
  const int    n0 = blockIdx.y * 128;

  f32x4 acc[4][4] = {};
  for (int k0 = 0; k0 < 512; k0 += 64) {
    #pragma unroll
    for (int it = 0; it < 4; ++it) {
      int idx = it * 256 + tid;
      int row = idx >> 3, c8 = (idx & 7) * 8;
      *reinterpret_cast<uint4*>(&As[row][c8]) =
          *reinterpret_cast<const uint4*>(A + (m0 + row) * 512 + k0 + c8);
      *reinterpret_cast<uint4*>(&Bs[row][c8]) =
          *reinterpret_cast<const uint4*>(B + (size_t)(n0 + row) * 512 + k0 + c8);
    }
    __syncthreads();
    #pragma unroll
    for (int kc = 0; kc < 2; ++kc) {
      bf16x8 a[4], b[4];
      #pragma unroll
      for (int i = 0; i < 4; ++i)
        a[i] = *reinterpret_cast<const bf16x8*>(&As[wm + i*16 + l15][kc*32 + quad*8]);
      #pragma unroll
      for (int j = 0; j < 4; ++j)
        b[j] = *reinterpret_cast<const bf16x8*>(&Bs[wn + j*16 + l15][kc*32 + quad*8]);
      #pragma unroll
      for (int i = 0; i < 4; ++i)
        #pragma unroll
        for (int j = 0; j < 4; ++j)
          acc[i][j] = __builtin_amdgcn_mfma_f32_16x16x32_bf16(a[i], b[j], acc[i][j], 0, 0, 0);
    }
    __syncthreads();
  }
  #pragma unroll
  for (int i = 0; i < 4; ++i) {
    #pragma unroll
    for (int j = 0; j < 4; ++j) {
      int gcol = n0 + wn + j*16 + l15;
      #pragma unroll
      for (int r = 0; r < 4; ++r) {
        size_t grow = m0 + wm + i*16 + quad*4 + r;
        cstore(C + grow * 512 + gcol, acc[i][j][r]);
      }
    }
  }
}

// ------------------------------------------------------------------
// Flash attention, one block per (qt, h, n). 4 waves, each owns 16 Q rows.
// RoPE fused into Q/K staging; V transposed into LDS at stage time.
// Epilogue: pad-mask + residual, writes y[t][n][d] bf16.
// ------------------------------------------------------------------
__global__ __launch_bounds__(256, 2) void attn_kernel(
    const unsigned short* __restrict__ qb,
    const unsigned short* __restrict__ kb,
    const unsigned short* __restrict__ vb,
    const unsigned short* __restrict__ xt,   // residual [n][t][d]
    const int* __restrict__ pad,             // [128]
    unsigned short* __restrict__ y)          // [t][n][d]
{
  const int qt = blockIdx.x;   // 0..5
  const int h  = blockIdx.y;   // 0..7
  const int n  = blockIdx.z;   // 0..127
  __shared__ alignas(16) unsigned short Qs[64][72];
  __shared__ alignas(16) unsigned short Ks[64][72];
  __shared__ alignas(16) unsigned short VTs[64][72];     // [dh][t]
  __shared__ alignas(16) unsigned short Ps[4][16][72];   // per-wave P

  const int tid  = threadIdx.x;
  const int wave = tid >> 6, lane = tid & 63;
  const int l15  = lane & 15, quad = lane >> 4;
  const float ROPE_C = 0.8304820237218406f;  // log2(10000)/16

  // ---- stage Q (+RoPE) ----
  #pragma unroll
  for (int it = 0; it < 2; ++it) {
    int idx = it * 256 + tid;
    int row = idx >> 3, c8 = idx & 7;
    int tg = qt * 64 + row;
    union { uint4 v; unsigned short u[8]; } p;
    p.v = *reinterpret_cast<const uint4*>(
        qb + ((size_t)(n * T_SEQ + tg)) * 512 + h * 64 + c8 * 8);
    if (c8 < 4) {
      #pragma unroll
      for (int j = 0; j < 4; ++j) {
        int i = c8 * 4 + j;
        float invf = exp2f(-(float)i * ROPE_C);
        float s, c; __sincosf((float)tg * invf, &s, &c);
        float a = bf2f(p.u[2*j]), b = bf2f(p.u[2*j+1]);
        p.u[2*j]   = f2bf(a * c - b * s);
        p.u[2*j+1] = f2bf(a * s + b * c);
      }
    }
    *reinterpret_cast<uint4*>(&Qs[row][c8 * 8]) = p.v;
  }

  float mrow[4], lrow[4];
  f32x4 oacc[4] = {};
  #pragma unroll
  for (int r = 0; r < 4; ++r) { mrow[r] = -INFINITY; lrow[r] = 0.f; }

  for (int kt = 0; kt <= qt; ++kt) {
    // ---- stage K (+RoPE) ----
    #pragma unroll
    for (int it = 0; it < 2; ++it) {
      int idx = it * 256 + tid;
      int row = idx >> 3, c8 = idx & 7;
      int tg = kt * 64 + row;
      union { uint4 v; unsigned short u[8]; } p;
      p.v = *reinterpret_cast<const uint4*>(
          kb + ((size_t)(n * T_SEQ + tg)) * 512 + h * 64 + c8 * 8);
      if (c8 < 4) {
        #pragma unroll
        for (int j = 0; j < 4; ++j) {
          int i = c8 * 4 + j;
          float invf = exp2f(-(float)i * ROPE_C);
          float s, c; __sincosf((float)tg * invf, &s, &c);
          float a = bf2f(p.u[2*j]), b = bf2f(p.u[2*j+1]);
          p.u[2*j]   = f2bf(a * c - b * s);
          p.u[2*j+1] = f2bf(a * s + b * c);
        }
      }
      *reinterpret_cast<uint4*>(&Ks[row][c8 * 8]) = p.v;
    }
    // ---- stage V transposed: VTs[dh][t] ----
    #pragma unroll
    for (int it = 0; it < 2; ++it) {
      int idx = it * 256 + tid;
      int dh = idx & 63, t8 = idx >> 6;   // t8 in 0..7 across the 2 iters
      union { uint4 v; unsigned short u[8]; } p;
      #pragma unroll
      for (int s = 0; s < 8; ++s)
        p.u[s] = vb[((size_t)(n * T_SEQ + kt * 64 + t8 * 8 + s)) * 512 + h * 64 + dh];
      *reinterpret_cast<uint4*>(&VTs[dh][t8 * 8]) = p.v;
    }
    __syncthreads();

    // ---- S = Q K^T (16 rows x 64 cols per wave) ----
    f32x4 sc4[4] = {};
    #pragma unroll
    for (int kc = 0; kc < 2; ++kc) {
      bf16x8 aq = *reinterpret_cast<const bf16x8*>(&Qs[wave*16 + l15][kc*32 + quad*8]);
      #pragma unroll
      for (int tc = 0; tc < 4; ++tc) {
        bf16x8 bk = *reinterpret_cast<const bf16x8*>(&Ks[tc*16 + l15][kc*32 + quad*8]);
        sc4[tc] = __builtin_amdgcn_mfma_f32_16x16x32_bf16(aq, bk, sc4[tc], 0, 0, 0);
      }
    }
    // ---- scale + causal mask ----
    float sv[4][4];
    #pragma unroll
    for (int tc = 0; tc < 4; ++tc)
      #pragma unroll
      for (int r = 0; r < 4; ++r) {
        float s = sc4[tc][r] * 0.125f;
        if (kt == qt) {
          int trow = qt*64 + wave*16 + quad*4 + r;
          int tcol = kt*64 + tc*16 + l15;
          if (tcol > trow) s = -1e30f;
        }
        sv[tc][r] = s;
      }
    // ---- online softmax (row stats via quad-group shuffles) ----
    #pragma unroll
    for (int r = 0; r < 4; ++r) {
      float m = fmaxf(fmaxf(sv[0][r], sv[1][r]), fmaxf(sv[2][r], sv[3][r]));
      m = fmaxf(m, __shfl_xor(m, 1));
      m = fmaxf(m, __shfl_xor(m, 2));
      m = fmaxf(m, __shfl_xor(m, 4));
      m = fmaxf(m, __shfl_xor(m, 8));
      float mnew  = fmaxf(mrow[r], m);
      float alpha = __expf(mrow[r] - mnew);
      float psum = 0.f;
      #pragma unroll
      for (int tc = 0; tc < 4; ++tc) {
        float p = __expf(sv[tc][r] - mnew);
        sv[tc][r] = p; psum += p;
      }
      psum += __shfl_xor(psum, 1);
      psum += __shfl_xor(psum, 2);
      psum += __shfl_xor(psum, 4);
      psum += __shfl_xor(psum, 8);
      lrow[r] = lrow[r] * alpha + psum;
      mrow[r] = mnew;
      #pragma unroll
      for (int dt = 0; dt < 4; ++dt) oacc[dt][r] = oacc[dt][r] * alpha;
      #pragma unroll
      for (int tc = 0; tc < 4; ++tc)
        Ps[wave][quad*4 + r][tc*16 + l15] = f2bf(sv[tc][r]);
    }
    // ---- O += P V ----
    #pragma unroll
    for (int kc = 0; kc < 2; ++kc) {
      bf16x8 ap = *reinterpret_cast<const bf16x8*>(&Ps[wave][l15][kc*32 + quad*8]);
      #pragma unroll
      for (int dt = 0; dt < 4; ++dt) {
        bf16x8 bv = *reinterpret_cast<const bf16x8*>(&VTs[dt*16 + l15][kc*32 + quad*8]);
        oacc[dt] = __builtin_amdgcn_mfma_f32_16x16x32_bf16(ap, bv, oacc[dt], 0, 0, 0);
      }
    }
    __syncthreads();
  }

  // ---- epilogue: mask + residual, write y[t][n][d] ----
  bool valid = (pad[n] != 0);
  #pragma unroll
  for (int dt = 0; dt < 4; ++dt)
    #pragma unroll
    for (int r = 0; r < 4; ++r) {
      int tq = qt*64 + wave*16 + quad*4 + r;
      int d  = h*64 + dt*16 + l15;
      float val = valid ? (oacc[dt][r] / lrow[r]) : 0.f;
      float res = bf2f(xt[((size_t)n * T_SEQ + tq) * 512 + d]);
      y[((size_t)tq * NNEUR + n) * 512 + d] = f2bf(val + res);
    }
}

// ------------------------------------------------------------------
extern "C" void kernel_launch(void* const* d_in, const int* in_sizes, int n_in,
                              void* d_out, int out_size, void* d_ws, size_t ws_size,
                              hipStream_t stream) {
  const float* x   = (const float*)d_in[0];
  const int*   pad = (const int*)d_in[1];
  const float* nw  = (const float*)d_in[2];
  const float* wq  = (const float*)d_in[3];
  const float* wk  = (const float*)d_in[4];
  const float* wv  = (const float*)d_in[5];
  const float* wo  = (const float*)d_in[6];
  float* out = (float*)d_out;

  char* ws = (char*)d_ws;
  size_t off = 0;
  auto alloc = [&](size_t bytes) { void* p = ws + off; off += (bytes + 255) & ~(size_t)255; return p; };
  const size_t WBYTES = (size_t)512 * 512 * 2;
  const size_t MBYTES = (size_t)NROWS * 512 * 2;
  unsigned short* wq_bf = (unsigned short*)alloc(WBYTES);
  unsigned short* wk_bf = (unsigned short*)alloc(WBYTES);
  unsigned short* wv_bf = (unsigned short*)alloc(WBYTES);
  unsigned short* wo_bf = (unsigned short*)alloc(WBYTES);
  unsigned short* xt_bf = (unsigned short*)alloc(MBYTES);
  unsigned short* q_buf = (unsigned short*)alloc(MBYTES);
  unsigned short* k_buf = (unsigned short*)alloc(MBYTES);
  unsigned short* v_buf = (unsigned short*)alloc(MBYTES);
  unsigned short* y_buf = (unsigned short*)alloc(MBYTES);

  cvt_w_kernel<<<dim3(256, 4), 256, 0, stream>>>(wq, wk, wv, wo, wq_bf, wk_bf, wv_bf, wo_bf);
  rmsnorm_kernel<<<NROWS / 4, 256, 0, stream>>>(x, nw, xt_bf);
  gemm_nt<unsigned short><<<dim3(NROWS / 128, 4), 256, 0, stream>>>(xt_bf, wq_bf, q_buf);
  gemm_nt<unsigned short><<<dim3(NROWS / 128, 4), 256, 0, stream>>>(xt_bf, wk_bf, k_buf);
  gemm_nt<unsigned short><<<dim3(NROWS / 128, 4), 256, 0, stream>>>(xt_bf, wv_bf, v_buf);
  attn_kernel<<<dim3(6, 8, 128), 256, 0, stream>>>(q_buf, k_buf, v_buf, xt_bf, pad, y_buf);
  gemm_nt<float><<<dim3(NROWS / 128, 4), 256, 0, stream>>>(y_buf, wo_bf, out);
}

// Round 2
// 441.372 us; speedup vs baseline: 1.1071x; 1.1071x over previous
//
#include <hip/hip_runtime.h>
#include <hip/hip_bf16.h>
#include <stdint.h>

typedef __bf16 bf16x8 __attribute__((ext_vector_type(8)));
typedef float f32x4 __attribute__((ext_vector_type(4)));

static constexpr int T_SEQ  = 384;
static constexpr int NNEUR  = 128;
static constexpr int DMODEL = 512;
static constexpr int NROWS  = NNEUR * T_SEQ;   // 49152
static constexpr float ROPE_C = 0.8304820237218406f;  // log2(10000)/16

__device__ __forceinline__ float bf2f(unsigned short u) {
  union { unsigned int i; float f; } x; x.i = ((unsigned int)u) << 16; return x.f;
}
__device__ __forceinline__ unsigned short f2bf(float f) {
  union { float f; unsigned int i; } x; x.f = f;
  unsigned int i = x.i;
  i += 0x7FFFu + ((i >> 16) & 1u);   // RNE
  return (unsigned short)(i >> 16);
}

// async global->LDS, 16B per lane; LDS dest = wave-uniform base + lane*16
__device__ __forceinline__ void async_copy16(const unsigned short* g, unsigned short* l) {
  auto gp = reinterpret_cast<const __attribute__((address_space(1))) unsigned int*>(
      reinterpret_cast<uintptr_t>(g));
  auto lp = reinterpret_cast<__attribute__((address_space(3))) unsigned int*>(
      reinterpret_cast<uintptr_t>(l));
  __builtin_amdgcn_global_load_lds(gp, lp, 16, 0, 0);
}

// ------------------------------------------------------------------
// weights fp32 -> bf16
// ------------------------------------------------------------------
__global__ __launch_bounds__(256) void cvt_w_kernel(
    const float* __restrict__ w0, const float* __restrict__ w1,
    const float* __restrict__ w2, const float* __restrict__ w3,
    unsigned short* __restrict__ o0, unsigned short* __restrict__ o1,
    unsigned short* __restrict__ o2, unsigned short* __restrict__ o3)
{
  const float* w; unsigned short* o;
  switch (blockIdx.y) {
    case 0:  w = w0; o = o0; break;
    case 1:  w = w1; o = o1; break;
    case 2:  w = w2; o = o2; break;
    default: w = w3; o = o3; break;
  }
  int i = (blockIdx.x * 256 + threadIdx.x) * 4;
  float4 v = *reinterpret_cast<const float4*>(w + i);
  union { unsigned short u[4]; uint2 v2; } p;
  p.u[0] = f2bf(v.x); p.u[1] = f2bf(v.y); p.u[2] = f2bf(v.z); p.u[3] = f2bf(v.w);
  *reinterpret_cast<uint2*>(o + i) = p.v2;
}

// ------------------------------------------------------------------
// RMSNorm: x[t][n][d] fp32 -> xt_bf[n][t][d] bf16 (also the residual)
// ------------------------------------------------------------------
__global__ __launch_bounds__(256) void rmsnorm_kernel(
    const float* __restrict__ x, const float* __restrict__ nw,
    unsigned short* __restrict__ xt)
{
  int wave = threadIdx.x >> 6, lane = threadIdx.x & 63;
  int rid = blockIdx.x * 4 + wave;       // rid = t*128 + n
  int t = rid >> 7, n = rid & 127;
  const float* row = x + (size_t)rid * DMODEL;
  float4 v0 = *reinterpret_cast<const float4*>(row + lane * 8);
  float4 v1 = *reinterpret_cast<const float4*>(row + lane * 8 + 4);
  float ss = v0.x*v0.x + v0.y*v0.y + v0.z*v0.z + v0.w*v0.w
           + v1.x*v1.x + v1.y*v1.y + v1.z*v1.z + v1.w*v1.w;
  #pragma unroll
  for (int off = 32; off; off >>= 1) ss += __shfl_xor(ss, off);
  float sc = rsqrtf(ss * (1.0f / DMODEL) + 1e-6f);
  float4 w0 = *reinterpret_cast<const float4*>(nw + lane * 8);
  float4 w1 = *reinterpret_cast<const float4*>(nw + lane * 8 + 4);
  union { unsigned short u[8]; uint4 v; } p;
  p.u[0] = f2bf(v0.x * sc * w0.x); p.u[1] = f2bf(v0.y * sc * w0.y);
  p.u[2] = f2bf(v0.z * sc * w0.z); p.u[3] = f2bf(v0.w * sc * w0.w);
  p.u[4] = f2bf(v1.x * sc * w1.x); p.u[5] = f2bf(v1.y * sc * w1.y);
  p.u[6] = f2bf(v1.z * sc * w1.z); p.u[7] = f2bf(v1.w * sc * w1.w);
  *reinterpret_cast<uint4*>(xt + ((size_t)n * T_SEQ + t) * DMODEL + lane * 8) = p.v;
}

// ------------------------------------------------------------------
// GEMM core: D[m][n] = sum_k A[m][k] * B[n][k] (both k-contiguous, bf16)
// 128x128 tile, BK=64, 4 waves 2x2, 16x16x32 MFMA, global_load_lds w/
// XOR chunk swizzle (physical chunk = logical ^ (row&7)).
// MODE 0: fp32 row-major out (row len 512)
// MODE 2: bf16 row-major out + RoPE on first 32 of each 64-dim head
// MODE 3: bf16 transposed store -> vt[n][dout][t] (A=W rows, B=Xt rows)
// ------------------------------------------------------------------
template <int MODE, typename OutT>
__global__ __launch_bounds__(256, 2) void gemm_k(
    const unsigned short* __restrict__ A,
    const unsigned short* __restrict__ B,
    OutT* __restrict__ C)
{
  __shared__ alignas(16) unsigned short As[128 * 64];
  __shared__ alignas(16) unsigned short Bs[128 * 64];
  const int tid  = threadIdx.x;
  const int wave = tid >> 6, lane = tid & 63;
  const int l15  = lane & 15, quad = lane >> 4;
  const int wm = (wave >> 1) * 64, wn = (wave & 1) * 64;
  const size_t m0 = (size_t)blockIdx.x * 128;
  const int    n0 = blockIdx.y * 128;
  const int lrow = lane >> 3;                       // 0..7
  const int lchunk = (lane & 7) ^ (lrow & 7);       // swizzled global chunk

  const unsigned short* ga = A + (m0 + wave * 32 + lrow) * 512 + lchunk * 8;
  const unsigned short* gb = B + ((size_t)n0 + wave * 32 + lrow) * 512 + lchunk * 8;
  unsigned short* lab = &As[(wave * 32) * 64];
  unsigned short* lbb = &Bs[(wave * 32) * 64];

  f32x4 acc[4][4] = {};
  for (int k0 = 0; k0 < 512; k0 += 64) {
    #pragma unroll
    for (int i = 0; i < 4; ++i) {
      async_copy16(ga + (size_t)(8 * i) * 512 + k0, lab + (8 * i) * 64);
      async_copy16(gb + (size_t)(8 * i) * 512 + k0, lbb + (8 * i) * 64);
    }
    __syncthreads();
    #pragma unroll
    for (int kc = 0; kc < 2; ++kc) {
      bf16x8 a[4], b[4];
      #pragma unroll
      for (int i = 0; i < 4; ++i) {
        int R = wm + i * 16 + l15;
        a[i] = *reinterpret_cast<const bf16x8*>(
            &As[R * 64 + (((kc * 4 + quad) ^ (l15 & 7)) * 8)]);
      }
      #pragma unroll
      for (int j = 0; j < 4; ++j) {
        int R = wn + j * 16 + l15;
        b[j] = *reinterpret_cast<const bf16x8*>(
            &Bs[R * 64 + (((kc * 4 + quad) ^ (l15 & 7)) * 8)]);
      }
      #pragma unroll
      for (int i = 0; i < 4; ++i)
        #pragma unroll
        for (int j = 0; j < 4; ++j)
          acc[i][j] = __builtin_amdgcn_mfma_f32_16x16x32_bf16(a[i], b[j], acc[i][j], 0, 0, 0);
    }
    __syncthreads();
  }

  // ---- epilogue ----
  const int base_t = (int)(m0 % 384);       // MODE 2: t = base_t + local row
  const int nn     = n0 / 384;              // MODE 3: neuron index
  #pragma unroll
  for (int i = 0; i < 4; ++i) {
    #pragma unroll
    for (int j = 0; j < 4; ++j) {
      float invf = 0.f;
      if constexpr (MODE == 2) {
        if (j < 2) invf = exp2f(-(float)(j * 8 + (l15 >> 1)) * ROPE_C);
      }
      #pragma unroll
      for (int r = 0; r < 4; ++r) {
        float v = acc[i][j][r];
        if constexpr (MODE == 2) {
          if (j < 2) {   // rotary half (uniform branch: dloc = j*16+l15 < 32)
            float part = __shfl_xor(v, 1);
            int t = base_t + wm + i * 16 + quad * 4 + r;
            float s, c; __sincosf((float)t * invf, &s, &c);
            v = (l15 & 1) ? (part * s + v * c) : (v * c - part * s);
          }
        }
        if constexpr (MODE == 3) {
          int trow = n0 + wn + j * 16 + l15;
          int dout = (int)m0 + wm + i * 16 + quad * 4 + r;
          C[((size_t)nn * 512 + dout) * 384 + (trow - nn * 384)] = f2bf(v);
        } else {
          int gcol = n0 + wn + j * 16 + l15;
          size_t grow = m0 + wm + i * 16 + quad * 4 + r;
          if constexpr (MODE == 0) C[grow * 512 + gcol] = v;
          else                     C[grow * 512 + gcol] = f2bf(v);
        }
      }
    }
  }
}

// ------------------------------------------------------------------
// Flash attention. Q/K already RoPE'd; V pre-transposed (vt[n][d][t]).
// One block per (qt, h, n); all staging via global_load_lds w/ swizzle.
// ------------------------------------------------------------------
__global__ __launch_bounds__(256, 4) void attn_kernel(
    const unsigned short* __restrict__ qb,   // [n][t][512]
    const unsigned short* __restrict__ kb,   // [n][t][512]
    const unsigned short* __restrict__ vt,   // [n][512][384]
    const unsigned short* __restrict__ xt,   // residual [n][t][512]
    const int* __restrict__ pad,             // [128]
    unsigned short* __restrict__ y)          // [t][n][512]
{
  const int qt = blockIdx.x;   // 0..5
  const int h  = blockIdx.y;   // 0..7
  const int n  = blockIdx.z;   // 0..127
  __shared__ alignas(16) unsigned short Qs[64 * 64];
  __shared__ alignas(16) unsigned short Ks[64 * 64];
  __shared__ alignas(16) unsigned short VTs[64 * 64];
  __shared__ alignas(16) unsigned short Ps[4][16][72];

  const int tid  = threadIdx.x;
  const int wave = tid >> 6, lane = tid & 63;
  const int l15  = lane & 15, quad = lane >> 4;
  const int lrow = lane >> 3, lchunk = (lane & 7) ^ ((lane >> 3) & 7);

  // stage Q once (rows wave*16 + 8i + lrow)
  const unsigned short* gq =
      qb + ((size_t)n * T_SEQ + qt * 64 + wave * 16 + lrow) * 512 + h * 64 + lchunk * 8;
  async_copy16(gq,            &Qs[(wave * 16) * 64]);
  async_copy16(gq + 8 * 512,  &Qs[(wave * 16 + 8) * 64]);

  const unsigned short* gk0 =
      kb + ((size_t)n * T_SEQ + wave * 16 + lrow) * 512 + h * 64 + lchunk * 8;
  const unsigned short* gv0 =
      vt + ((size_t)n * 512 + h * 64 + wave * 16 + lrow) * 384 + lchunk * 8;

  float mrow[4], lsum[4];
  f32x4 oacc[4] = {};
  #pragma unroll
  for (int r = 0; r < 4; ++r) { mrow[r] = -INFINITY; lsum[r] = 0.f; }

  for (int kt = 0; kt <= qt; ++kt) {
    async_copy16(gk0 + (size_t)(kt * 64) * 512,     &Ks[(wave * 16) * 64]);
    async_copy16(gk0 + (size_t)(kt * 64 + 8) * 512, &Ks[(wave * 16 + 8) * 64]);
    async_copy16(gv0 + kt * 64,                     &VTs[(wave * 16) * 64]);
    async_copy16(gv0 + kt * 64 + 8 * 384,           &VTs[(wave * 16 + 8) * 64]);
    __syncthreads();

    // ---- S = Q K^T ----
    f32x4 sc4[4] = {};
    #pragma unroll
    for (int kc = 0; kc < 2; ++kc) {
      bf16x8 aq = *reinterpret_cast<const bf16x8*>(
          &Qs[(wave * 16 + l15) * 64 + (((kc * 4 + quad) ^ (l15 & 7)) * 8)]);
      #pragma unroll
      for (int tc = 0; tc < 4; ++tc) {
        bf16x8 bk = *reinterpret_cast<const bf16x8*>(
            &Ks[(tc * 16 + l15) * 64 + (((kc * 4 + quad) ^ (l15 & 7)) * 8)]);
        sc4[tc] = __builtin_amdgcn_mfma_f32_16x16x32_bf16(aq, bk, sc4[tc], 0, 0, 0);
      }
    }
    // ---- scale + causal mask ----
    float sv[4][4];
    #pragma unroll
    for (int tc = 0; tc < 4; ++tc)
      #pragma unroll
      for (int r = 0; r < 4; ++r) {
        float s = sc4[tc][r] * 0.125f;
        if (kt == qt) {
          int trow = wave * 16 + quad * 4 + r;
          int tcol = tc * 16 + l15;
          if (tcol > trow) s = -1e30f;
        }
        sv[tc][r] = s;
      }
    // ---- online softmax ----
    #pragma unroll
    for (int r = 0; r < 4; ++r) {
      float m = fmaxf(fmaxf(sv[0][r], sv[1][r]), fmaxf(sv[2][r], sv[3][r]));
      m = fmaxf(m, __shfl_xor(m, 1));
      m = fmaxf(m, __shfl_xor(m, 2));
      m = fmaxf(m, __shfl_xor(m, 4));
      m = fmaxf(m, __shfl_xor(m, 8));
      float mnew  = fmaxf(mrow[r], m);
      float alpha = __expf(mrow[r] - mnew);
      float psum = 0.f;
      #pragma unroll
      for (int tc = 0; tc < 4; ++tc) {
        float p = __expf(sv[tc][r] - mnew);
        sv[tc][r] = p; psum += p;
      }
      psum += __shfl_xor(psum, 1);
      psum += __shfl_xor(psum, 2);
      psum += __shfl_xor(psum, 4);
      psum += __shfl_xor(psum, 8);
      lsum[r] = lsum[r] * alpha + psum;
      mrow[r] = mnew;
      #pragma unroll
      for (int dt = 0; dt < 4; ++dt) oacc[dt][r] = oacc[dt][r] * alpha;
      #pragma unroll
      for (int tc = 0; tc < 4; ++tc)
        Ps[wave][quad * 4 + r][tc * 16 + l15] = f2bf(sv[tc][r]);
    }
    // ---- O += P V ----
    #pragma unroll
    for (int kc = 0; kc < 2; ++kc) {
      bf16x8 ap = *reinterpret_cast<const bf16x8*>(&Ps[wave][l15][kc * 32 + quad * 8]);
      #pragma unroll
      for (int dt = 0; dt < 4; ++dt) {
        bf16x8 bv = *reinterpret_cast<const bf16x8*>(
            &VTs[(dt * 16 + l15) * 64 + (((kc * 4 + quad) ^ (l15 & 7)) * 8)]);
        oacc[dt] = __builtin_amdgcn_mfma_f32_16x16x32_bf16(ap, bv, oacc[dt], 0, 0, 0);
      }
    }
    __syncthreads();
  }

  // ---- epilogue: mask + residual, write y[t][n][d] ----
  bool valid = (pad[n] != 0);
  #pragma unroll
  for (int dt = 0; dt < 4; ++dt)
    #pragma unroll
    for (int r = 0; r < 4; ++r) {
      int tq = qt * 64 + wave * 16 + quad * 4 + r;
      int d  = h * 64 + dt * 16 + l15;
      float val = valid ? (oacc[dt][r] / lsum[r]) : 0.f;
      float res = bf2f(xt[((size_t)n * T_SEQ + tq) * 512 + d]);
      y[((size_t)tq * NNEUR + n) * 512 + d] = f2bf(val + res);
    }
}

// ------------------------------------------------------------------
extern "C" void kernel_launch(void* const* d_in, const int* in_sizes, int n_in,
                              void* d_out, int out_size, void* d_ws, size_t ws_size,
                              hipStream_t stream) {
  const float* x   = (const float*)d_in[0];
  const int*   pad = (const int*)d_in[1];
  const float* nw  = (const float*)d_in[2];
  const float* wq  = (const float*)d_in[3];
  const float* wk  = (const float*)d_in[4];
  const float* wv  = (const float*)d_in[5];
  const float* wo  = (const float*)d_in[6];
  float* out = (float*)d_out;

  char* ws = (char*)d_ws;
  size_t off = 0;
  auto alloc = [&](size_t bytes) { void* p = ws + off; off += (bytes + 255) & ~(size_t)255; return p; };
  const size_t WBYTES = (size_t)512 * 512 * 2;
  const size_t MBYTES = (size_t)NROWS * 512 * 2;
  unsigned short* wq_bf = (unsigned short*)alloc(WBYTES);
  unsigned short* wk_bf = (unsigned short*)alloc(WBYTES);
  unsigned short* wv_bf = (unsigned short*)alloc(WBYTES);
  unsigned short* wo_bf = (unsigned short*)alloc(WBYTES);
  unsigned short* xt_bf = (unsigned short*)alloc(MBYTES);
  unsigned short* q_buf = (unsigned short*)alloc(MBYTES);
  unsigned short* k_buf = (unsigned short*)alloc(MBYTES);
  unsigned short* vt_buf= (unsigned short*)alloc(MBYTES);
  unsigned short* y_buf = (unsigned short*)alloc(MBYTES);

  cvt_w_kernel<<<dim3(256, 4), 256, 0, stream>>>(wq, wk, wv, wo, wq_bf, wk_bf, wv_bf, wo_bf);
  rmsnorm_kernel<<<NROWS / 4, 256, 0, stream>>>(x, nw, xt_bf);
  // Q = Xt Wq^T (+RoPE), K = Xt Wk^T (+RoPE): row-major bf16
  gemm_k<2, unsigned short><<<dim3(NROWS / 128, 4), 256, 0, stream>>>(xt_bf, wq_bf, q_buf);
  gemm_k<2, unsigned short><<<dim3(NROWS / 128, 4), 256, 0, stream>>>(xt_bf, wk_bf, k_buf);
  // V^T: D[dout][trow] = sum_k Wv[dout][k] Xt[trow][k] -> vt[n][d][t]
  gemm_k<3, unsigned short><<<dim3(4, NROWS / 128), 256, 0, stream>>>(wv_bf, xt_bf, vt_buf);
  attn_kernel<<<dim3(6, 8, 128), 256, 0, stream>>>(q_buf, k_buf, vt_buf, xt_bf, pad, y_buf);
  // out = y Wo^T, fp32
  gemm_k<0, float><<<dim3(NROWS / 128, 4), 256, 0, stream>>>(y_buf, wo_bf, out);
}

// Round 3
// 432.152 us; speedup vs baseline: 1.1307x; 1.0213x over previous
//
#include <hip/hip_runtime.h>
#include <hip/hip_bf16.h>
#include <stdint.h>

typedef __bf16 bf16x8 __attribute__((ext_vector_type(8)));
typedef float f32x4 __attribute__((ext_vector_type(4)));

static constexpr int T_SEQ  = 384;
static constexpr int NNEUR  = 128;
static constexpr int DMODEL = 512;
static constexpr int NROWS  = NNEUR * T_SEQ;   // 49152
static constexpr float ROPE_C = 0.8304820237218406f;  // log2(10000)/16

__device__ __forceinline__ float bf2f(unsigned short u) {
  union { unsigned int i; float f; } x; x.i = ((unsigned int)u) << 16; return x.f;
}
__device__ __forceinline__ unsigned short f2bf(float f) {
  union { float f; unsigned int i; } x; x.f = f;
  unsigned int i = x.i;
  i += 0x7FFFu + ((i >> 16) & 1u);   // RNE
  return (unsigned short)(i >> 16);
}
__device__ __forceinline__ float fast_exp2(float x) {
#if __has_builtin(__builtin_amdgcn_exp2f)
  return __builtin_amdgcn_exp2f(x);
#else
  return exp2f(x);
#endif
}

// async global->LDS, 16B per lane; LDS dest = wave-uniform base + lane*16
__device__ __forceinline__ void async_copy16(const unsigned short* g, unsigned short* l) {
  auto gp = reinterpret_cast<const __attribute__((address_space(1))) unsigned int*>(
      reinterpret_cast<uintptr_t>(g));
  auto lp = reinterpret_cast<__attribute__((address_space(3))) unsigned int*>(
      reinterpret_cast<uintptr_t>(l));
  __builtin_amdgcn_global_load_lds(gp, lp, 16, 0, 0);
}

// ------------------------------------------------------------------
// weights fp32 -> bf16
// ------------------------------------------------------------------
__global__ __launch_bounds__(256) void cvt_w_kernel(
    const float* __restrict__ w0, const float* __restrict__ w1,
    const float* __restrict__ w2, const float* __restrict__ w3,
    unsigned short* __restrict__ o0, unsigned short* __restrict__ o1,
    unsigned short* __restrict__ o2, unsigned short* __restrict__ o3)
{
  const float* w; unsigned short* o;
  switch (blockIdx.y) {
    case 0:  w = w0; o = o0; break;
    case 1:  w = w1; o = o1; break;
    case 2:  w = w2; o = o2; break;
    default: w = w3; o = o3; break;
  }
  int i = (blockIdx.x * 256 + threadIdx.x) * 4;
  float4 v = *reinterpret_cast<const float4*>(w + i);
  union { unsigned short u[4]; uint2 v2; } p;
  p.u[0] = f2bf(v.x); p.u[1] = f2bf(v.y); p.u[2] = f2bf(v.z); p.u[3] = f2bf(v.w);
  *reinterpret_cast<uint2*>(o + i) = p.v2;
}

// rope table: tab[t*16+i] = (sin, cos) of t * 10000^(-i/16)
__global__ __launch_bounds__(256) void rope_tab_kernel(float2* __restrict__ tab) {
  int idx = blockIdx.x * 256 + threadIdx.x;   // 6144
  int t = idx >> 4, i = idx & 15;
  float ang = (float)t * exp2f(-(float)i * ROPE_C);
  float s, c; sincosf(ang, &s, &c);
  tab[idx] = make_float2(s, c);
}

// ------------------------------------------------------------------
// RMSNorm: x[t][n][d] fp32 -> xt_bf[n][t][d] bf16 (also the residual)
// ------------------------------------------------------------------
__global__ __launch_bounds__(256) void rmsnorm_kernel(
    const float* __restrict__ x, const float* __restrict__ nw,
    unsigned short* __restrict__ xt)
{
  int wave = threadIdx.x >> 6, lane = threadIdx.x & 63;
  int rid = blockIdx.x * 4 + wave;       // rid = t*128 + n
  int t = rid >> 7, n = rid & 127;
  const float* row = x + (size_t)rid * DMODEL;
  float4 v0 = *reinterpret_cast<const float4*>(row + lane * 8);
  float4 v1 = *reinterpret_cast<const float4*>(row + lane * 8 + 4);
  float ss = v0.x*v0.x + v0.y*v0.y + v0.z*v0.z + v0.w*v0.w
           + v1.x*v1.x + v1.y*v1.y + v1.z*v1.z + v1.w*v1.w;
  #pragma unroll
  for (int off = 32; off; off >>= 1) ss += __shfl_xor(ss, off);
  float sc = rsqrtf(ss * (1.0f / DMODEL) + 1e-6f);
  float4 w0 = *reinterpret_cast<const float4*>(nw + lane * 8);
  float4 w1 = *reinterpret_cast<const float4*>(nw + lane * 8 + 4);
  union { unsigned short u[8]; uint4 v; } p;
  p.u[0] = f2bf(v0.x * sc * w0.x); p.u[1] = f2bf(v0.y * sc * w0.y);
  p.u[2] = f2bf(v0.z * sc * w0.z); p.u[3] = f2bf(v0.w * sc * w0.w);
  p.u[4] = f2bf(v1.x * sc * w1.x); p.u[5] = f2bf(v1.y * sc * w1.y);
  p.u[6] = f2bf(v1.z * sc * w1.z); p.u[7] = f2bf(v1.w * sc * w1.w);
  *reinterpret_cast<uint4*>(xt + ((size_t)n * T_SEQ + t) * DMODEL + lane * 8) = p.v;
}

// ------------------------------------------------------------------
// GEMM: D[m][n] = sum_k A[m][k]*B[n][k], bf16 in, fp32 acc.
// 256x128 tile, BK=64, 512 threads / 8 waves (4m x 2n), 16x16x32 MFMA,
// global_load_lds staging with XOR chunk swizzle.
// MODE 0: fp32 row-major store (out = y Wo^T)
// MODE 2: bf16 row-major store + table RoPE; C covers q|k sections (n0>>9)
// MODE 3: bf16 transposed + k-permuted store -> vt[nn][dout][kperm(t)]
// ------------------------------------------------------------------
template <int MODE, typename OutT>
__global__ __launch_bounds__(512, 4) void gemm_k(
    const unsigned short* __restrict__ A,
    const unsigned short* __restrict__ B,
    OutT* __restrict__ C,
    const float2* __restrict__ tab)
{
  __shared__ alignas(16) unsigned short Sh[384 * 64];   // rows 0-255 A, 256-383 B
  const int tid  = threadIdx.x;
  const int wave = tid >> 6, lane = tid & 63;
  const int l15  = lane & 15, quad = lane >> 4;
  const int wm = (wave >> 1) * 64, wn = (wave & 1) * 64;
  size_t m0; int n0;
  if constexpr (MODE == 3) { m0 = (size_t)blockIdx.x * 256; n0 = blockIdx.y * 128; }
  else                     { m0 = (size_t)blockIdx.y * 256; n0 = blockIdx.x * 128; }

  const int srow  = tid >> 3;                       // 0..63
  const int schunk = (tid & 7) ^ (srow & 7);        // swizzled global chunk
  const unsigned short* ga = A + (m0 + srow) * 512 + schunk * 8;
  const unsigned short* gb = B + ((size_t)n0 + srow) * 512 + schunk * 8;
  unsigned short* ls = &Sh[tid * 8];

  f32x4 acc[4][4] = {};
  for (int k0 = 0; k0 < 512; k0 += 64) {
    #pragma unroll
    for (int ra = 0; ra < 4; ++ra)
      async_copy16(ga + (size_t)ra * 32768 + k0, ls + ra * 4096);
    #pragma unroll
    for (int rb = 0; rb < 2; ++rb)
      async_copy16(gb + (size_t)rb * 32768 + k0, ls + (4 + rb) * 4096);
    __syncthreads();
    #pragma unroll
    for (int kc = 0; kc < 2; ++kc) {
      const int pc = ((kc * 4 + quad) ^ (l15 & 7)) * 8;
      bf16x8 a[4], b[4];
      #pragma unroll
      for (int i = 0; i < 4; ++i)
        a[i] = *reinterpret_cast<const bf16x8*>(&Sh[(wm + i * 16 + l15) * 64 + pc]);
      #pragma unroll
      for (int j = 0; j < 4; ++j)
        b[j] = *reinterpret_cast<const bf16x8*>(&Sh[(256 + wn + j * 16 + l15) * 64 + pc]);
      #pragma unroll
      for (int i = 0; i < 4; ++i)
        #pragma unroll
        for (int j = 0; j < 4; ++j)
          acc[i][j] = __builtin_amdgcn_mfma_f32_16x16x32_bf16(a[i], b[j], acc[i][j], 0, 0, 0);
    }
    __syncthreads();
  }

  // ---- epilogue ----
  if constexpr (MODE == 3) {
    // element: (dout = m-row, xtrow = n-col). store vt[nn][dout][kperm(t)]
    #pragma unroll
    for (int j = 0; j < 4; ++j) {
      int xbase = n0 + wn + j * 16;            // multiple of 16
      int nn    = xbase / 384;
      int bloc  = xbase - nn * 384;
      int off64 = (bloc >> 6) * 64 + ((bloc >> 4) & 3);   // + l15*4 gives k'
      #pragma unroll
      for (int i = 0; i < 4; ++i)
        #pragma unroll
        for (int r = 0; r < 4; ++r) {
          int dout = (int)m0 + wm + i * 16 + quad * 4 + r;
          C[((size_t)nn * 512 + dout) * 384 + off64 + l15 * 4] = f2bf(acc[i][j][r]);
        }
    }
  } else {
    OutT* Cb = C;
    int ncol0 = n0 + wn;
    if constexpr (MODE == 2) {
      int sec = n0 >> 9;                        // 0=q, 1=k
      Cb = C + (size_t)sec * NROWS * 512;
      ncol0 = (n0 & 511) + wn;
    }
    #pragma unroll
    for (int i = 0; i < 4; ++i) {
      #pragma unroll
      for (int r = 0; r < 4; ++r) {
        size_t grow = m0 + wm + i * 16 + quad * 4 + r;
        int t = (int)(grow % 384);
        #pragma unroll
        for (int j = 0; j < 4; ++j) {
          float v = acc[i][j][r];
          int col = ncol0 + j * 16 + l15;
          if constexpr (MODE == 2) {
            if (((ncol0 + j * 16) & 63) < 32) {   // rotary half (wave-uniform)
              float part = __shfl_xor(v, 1);
              float2 scv = tab[t * 16 + ((col & 63) >> 1)];
              v = (l15 & 1) ? (part * scv.x + v * scv.y)
                            : (v * scv.y - part * scv.x);
            }
            Cb[grow * 512 + col] = f2bf(v);
          } else {
            Cb[grow * 512 + col] = v;   // fp32
          }
        }
      }
    }
  }
}

// ------------------------------------------------------------------
// Flash attention. Q/K pre-RoPE'd; V pre-transposed AND k-permuted
// (vt[n][d][k'], k' = (t&15)*4 + (t>>4) within each 64-tile).
// Fixed-max exp2 softmax (no online max), deferred lsum reduction.
// ------------------------------------------------------------------
__global__ __launch_bounds__(256, 4) void attn_kernel(
    const unsigned short* __restrict__ qb,   // [n][t][512]
    const unsigned short* __restrict__ kb,   // [n][t][512]
    const unsigned short* __restrict__ vt,   // [n][512][384] (k-permuted)
    const unsigned short* __restrict__ xt,   // residual [n][t][512]
    const int* __restrict__ pad,             // [128]
    unsigned short* __restrict__ y)          // [t][n][512]
{
  const int qt = blockIdx.x;   // 0..5
  const int h  = blockIdx.y;   // 0..7
  const int n  = blockIdx.z;   // 0..127
  __shared__ alignas(16) unsigned short Qs[64 * 64];
  __shared__ alignas(16) unsigned short Ks[64 * 64];
  __shared__ alignas(16) unsigned short VTs[64 * 64];
  __shared__ alignas(16) unsigned short Ps[4][16][72];

  const int tid  = threadIdx.x;
  const int wave = tid >> 6, lane = tid & 63;
  const int l15  = lane & 15, quad = lane >> 4;
  const int lrow = lane >> 3, lchunk = (lane & 7) ^ ((lane >> 3) & 7);
  const float C2 = 0.18033688011112042f;     // 0.125 * log2(e)

  const unsigned short* gq =
      qb + ((size_t)n * T_SEQ + qt * 64 + wave * 16 + lrow) * 512 + h * 64 + lchunk * 8;
  async_copy16(gq,           &Qs[(wave * 16) * 64]);
  async_copy16(gq + 8 * 512, &Qs[(wave * 16 + 8) * 64]);

  const unsigned short* gk0 =
      kb + ((size_t)n * T_SEQ + wave * 16 + lrow) * 512 + h * 64 + lchunk * 8;
  const unsigned short* gv0 =
      vt + ((size_t)n * 512 + h * 64 + wave * 16 + lrow) * 384 + lchunk * 8;

  float lsum[4] = {0.f, 0.f, 0.f, 0.f};
  f32x4 oacc[4] = {};

  for (int kt = 0; kt <= qt; ++kt) {
    async_copy16(gk0 + (size_t)(kt * 64) * 512,     &Ks[(wave * 16) * 64]);
    async_copy16(gk0 + (size_t)(kt * 64 + 8) * 512, &Ks[(wave * 16 + 8) * 64]);
    async_copy16(gv0 + kt * 64,                     &VTs[(wave * 16) * 64]);
    async_copy16(gv0 + kt * 64 + 8 * 384,           &VTs[(wave * 16 + 8) * 64]);
    __syncthreads();

    // ---- S = Q K^T ----
    f32x4 sc4[4] = {};
    #pragma unroll
    for (int kc = 0; kc < 2; ++kc) {
      const int pc = ((kc * 4 + quad) ^ (l15 & 7)) * 8;
      bf16x8 aq = *reinterpret_cast<const bf16x8*>(&Qs[(wave * 16 + l15) * 64 + pc]);
      #pragma unroll
      for (int tc = 0; tc < 4; ++tc) {
        bf16x8 bk = *reinterpret_cast<const bf16x8*>(&Ks[(tc * 16 + l15) * 64 + pc]);
        sc4[tc] = __builtin_amdgcn_mfma_f32_16x16x32_bf16(aq, bk, sc4[tc], 0, 0, 0);
      }
    }
    // ---- fixed-max exp2 softmax ----
    const bool diag = (kt == qt);
    float ps[4][4];
    #pragma unroll
    for (int tc = 0; tc < 4; ++tc)
      #pragma unroll
      for (int r = 0; r < 4; ++r) {
        float p = fast_exp2(sc4[tc][r] * C2 - 16.0f);
        if (diag && (tc * 16 + l15 > wave * 16 + quad * 4 + r)) p = 0.f;
        lsum[r] += p;
        ps[tc][r] = p;
      }
    // ---- pack P (trunc->bf16) into k'-permuted LDS: k' = l15*4 + tc ----
    #pragma unroll
    for (int r = 0; r < 4; ++r) {
      union { float f; unsigned int u; } a0, a1, a2, a3;
      a0.f = ps[0][r]; a1.f = ps[1][r]; a2.f = ps[2][r]; a3.f = ps[3][r];
      uint2 pk;
      pk.x = (a1.u & 0xffff0000u) | (a0.u >> 16);
      pk.y = (a3.u & 0xffff0000u) | (a2.u >> 16);
      *reinterpret_cast<uint2*>(&Ps[wave][quad * 4 + r][l15 * 4]) = pk;
    }
    // ---- O += P V (both sides k'-permuted) ----
    #pragma unroll
    for (int kc = 0; kc < 2; ++kc) {
      const int pc = ((kc * 4 + quad) ^ (l15 & 7)) * 8;
      bf16x8 ap = *reinterpret_cast<const bf16x8*>(&Ps[wave][l15][kc * 32 + quad * 8]);
      #pragma unroll
      for (int dt = 0; dt < 4; ++dt) {
        bf16x8 bv = *reinterpret_cast<const bf16x8*>(&VTs[(dt * 16 + l15) * 64 + pc]);
        oacc[dt] = __builtin_amdgcn_mfma_f32_16x16x32_bf16(ap, bv, oacc[dt], 0, 0, 0);
      }
    }
    __syncthreads();
  }

  // ---- lsum reduce + epilogue: mask + residual, write y[t][n][d] ----
  float inv[4];
  #pragma unroll
  for (int r = 0; r < 4; ++r) {
    float l = lsum[r];
    l += __shfl_xor(l, 1);
    l += __shfl_xor(l, 2);
    l += __shfl_xor(l, 4);
    l += __shfl_xor(l, 8);
    inv[r] = 1.0f / l;
  }
  bool valid = (pad[n] != 0);
  #pragma unroll
  for (int dt = 0; dt < 4; ++dt)
    #pragma unroll
    for (int r = 0; r < 4; ++r) {
      int tq = qt * 64 + wave * 16 + quad * 4 + r;
      int d  = h * 64 + dt * 16 + l15;
      float val = valid ? (oacc[dt][r] * inv[r]) : 0.f;
      float res = bf2f(xt[((size_t)n * T_SEQ + tq) * 512 + d]);
      y[((size_t)tq * NNEUR + n) * 512 + d] = f2bf(val + res);
    }
}

// ------------------------------------------------------------------
extern "C" void kernel_launch(void* const* d_in, const int* in_sizes, int n_in,
                              void* d_out, int out_size, void* d_ws, size_t ws_size,
                              hipStream_t stream) {
  const float* x   = (const float*)d_in[0];
  const int*   pad = (const int*)d_in[1];
  const float* nw  = (const float*)d_in[2];
  const float* wq  = (const float*)d_in[3];
  const float* wk  = (const float*)d_in[4];
  const float* wv  = (const float*)d_in[5];
  const float* wo  = (const float*)d_in[6];
  float* out = (float*)d_out;

  char* ws = (char*)d_ws;
  size_t off = 0;
  auto alloc = [&](size_t bytes) { void* p = ws + off; off += (bytes + 255) & ~(size_t)255; return p; };
  const size_t WELEM  = (size_t)512 * 512;        // elements per weight
  const size_t MBYTES = (size_t)NROWS * 512 * 2;
  unsigned short* wqkv_bf = (unsigned short*)alloc(WELEM * 3 * 2);
  unsigned short* wo_bf   = (unsigned short*)alloc(WELEM * 2);
  float2*         rtab    = (float2*)alloc(384 * 16 * sizeof(float2));
  unsigned short* xt_bf   = (unsigned short*)alloc(MBYTES);
  unsigned short* qk_buf  = (unsigned short*)alloc(MBYTES * 2);
  unsigned short* vt_buf  = (unsigned short*)alloc(MBYTES);
  unsigned short* y_buf   = (unsigned short*)alloc(MBYTES);

  cvt_w_kernel<<<dim3(256, 4), 256, 0, stream>>>(
      wq, wk, wv, wo,
      wqkv_bf, wqkv_bf + WELEM, wqkv_bf + 2 * WELEM, wo_bf);
  rope_tab_kernel<<<24, 256, 0, stream>>>(rtab);
  rmsnorm_kernel<<<NROWS / 4, 256, 0, stream>>>(x, nw, xt_bf);
  // fused Q|K GEMM (+RoPE): grid x = column block (8 -> n0 in [0,1024))
  gemm_k<2, unsigned short><<<dim3(8, NROWS / 256), 512, 0, stream>>>(
      xt_bf, wqkv_bf, qk_buf, rtab);
  // V^T (k-permuted): A = wv (512 rows), B = xt
  gemm_k<3, unsigned short><<<dim3(2, NROWS / 128), 512, 0, stream>>>(
      wqkv_bf + 2 * WELEM, xt_bf, vt_buf, nullptr);
  attn_kernel<<<dim3(6, 8, 128), 256, 0, stream>>>(
      qk_buf, qk_buf + (size_t)NROWS * 512, vt_buf, xt_bf, pad, y_buf);
  // out = y Wo^T (fp32)
  gemm_k<0, float><<<dim3(4, NROWS / 256), 512, 0, stream>>>(
      y_buf, wo_bf, out, nullptr);
}